// Round 14
// baseline (670.706 us; speedup 1.0000x reference)
//
#include <hip/hip_runtime.h>
#include <hip/hip_bf16.h>

#define NN 4096
#define FF 512
#define NH 8
#define DH 64

typedef __attribute__((ext_vector_type(8))) short bf16x8;
typedef __attribute__((ext_vector_type(4))) float f32x4;

// ws layout in ushort elements:
//  X_BF  [4096][512]                    @ 0
//  W_BF  [3][512][512]                  @ 2097152   (Wq pre-scaled by 1/sqrt(512))
//  QF    [8][256 blk][2 half][64 ln][8] @ 2883584   (MFMA fragment order)
//  KF    [8][256 blk][2 half][64 ln][8] @ 4980736   (MFMA fragment order)
//  VF    [8][64 kb][4 dt][2 hf][64][8]  @ 7077888   (MFMA B-fragment order, d-major)
//  PACC  bf16 [4 ks][8 h][4096][64]     @ 9175040   (8388608 ushorts)
//  PDEN  f32  [4 ks][8 h][4096]         @ 17563648  (262144 ushorts)
#define X_OFF  0
#define W_OFF  2097152
#define QF_OFF 2883584
#define KF_OFF 4980736
#define VF_OFF 7077888
#define PACC_OFF 9175040
#define PDEN_USHORT_OFF 17563648

__device__ __forceinline__ ushort f2bf(float f) {
    __hip_bfloat16 h = __float2bfloat16(f);
    return __builtin_bit_cast(ushort, h);
}
__device__ __forceinline__ float bf2f(ushort u) {
    unsigned int v = ((unsigned int)u) << 16;
    return __builtin_bit_cast(float, v);
}

// ---------------- kernel 0: f32 -> bf16 convert (x, Wq*scale, Wk, Wv) ----------------
__global__ __launch_bounds__(256) void cvt_kernel(const float* __restrict__ x,
                                                  const float* __restrict__ wq,
                                                  const float* __restrict__ wk,
                                                  const float* __restrict__ wv,
                                                  ushort* __restrict__ ws) {
    int i = blockIdx.x * 256 + threadIdx.x;
    int base = i * 4;
    const float* src;
    int off;
    float sc = 1.f;
    if (base < 2097152) { src = x; off = base; }
    else {
        int t = base - 2097152;
        int m = t >> 18;
        src = (m == 0) ? wq : ((m == 1) ? wk : wv);
        if (m == 0) sc = 0.044194173824159216f;   // 1/sqrt(512) folded into Wq
        off = t & 262143;
    }
    float4 v = *reinterpret_cast<const float4*>(src + off);
    ushort4 o;
    o.x = f2bf(v.x * sc); o.y = f2bf(v.y * sc); o.z = f2bf(v.z * sc); o.w = f2bf(v.w * sc);
    *reinterpret_cast<ushort4*>(ws + base) = o;
}

// ---------------- kernel 1: QKV projection, outputs in MFMA-fragment order ----------------
__global__ __launch_bounds__(256) void qkv_kernel(ushort* __restrict__ ws) {
    int bx = blockIdx.x;
    int mat = bx >> 3;          // 0=Q,1=K,2=V
    int fb  = bx & 7;           // head
    int mb  = blockIdx.y;
    int wave = threadIdx.x >> 6, lane = threadIdx.x & 63;
    int la = lane & 15, lk = lane >> 4;

    int m_base = mb * 64 + wave * 16;
    int f_base = fb * 64;

    const ushort* xb = ws + X_OFF;
    const ushort* wb = ws + W_OFF + mat * 262144;

    f32x4 acc[4];
#pragma unroll
    for (int t = 0; t < 4; ++t) acc[t] = (f32x4){0.f, 0.f, 0.f, 0.f};

#pragma unroll 4
    for (int k0 = 0; k0 < 512; k0 += 32) {
        bf16x8 a = *reinterpret_cast<const bf16x8*>(xb + (size_t)(m_base + la) * 512 + k0 + lk * 8);
#pragma unroll
        for (int ft = 0; ft < 4; ++ft) {
            bf16x8 b = *reinterpret_cast<const bf16x8*>(wb + (size_t)(f_base + ft * 16 + la) * 512 + k0 + lk * 8);
            acc[ft] = __builtin_amdgcn_mfma_f32_16x16x32_bf16(a, b, acc[ft], 0, 0, 0);
        }
    }

#pragma unroll
    for (int ft = 0; ft < 4; ++ft) {
#pragma unroll
        for (int r = 0; r < 4; ++r) {
            int n = m_base + lk * 4 + r;
            int d = ft * 16 + la;          // head-local feature
            ushort v = f2bf(acc[ft][r]);
            if (mat < 2) {
                ushort* base = ws + (mat == 0 ? QF_OFF : KF_OFF) + (size_t)fb * 262144;
                int blk = n >> 4, rr = n & 15;
                int half = d >> 5, lkk = (d >> 3) & 3, e = d & 7;
                base[(((size_t)blk * 2 + half) * 64 + lkk * 16 + rr) * 8 + e] = v;
            } else {
                ushort* base = ws + VF_OFF + (size_t)fb * 262144;
                int kb64 = n >> 6, kc = n & 63;
                int hf = kc >> 5, lkv = (kc >> 3) & 3, ev = kc & 7;
                int dt = d >> 4, lav = d & 15;
                base[((((size_t)kb64 * 4 + dt) * 2 + hf) * 64 + lkv * 16 + lav) * 8 + ev] = v;
            }
        }
    }
}

// ---------------- kernel 2: fused attention — swapped QK^T, ballot adj, no barriers ----
// grid 2048: h = bid&7 (XCD-pinned), qb = (bid>>3)&63, ks = bid>>9 (0..3).
// 4 waves x 16 q-rows; 16 bodies of 64 keys. Per body:
//   ballot(adjv loaded last body) -> 16 wave-uniform 64-bit row masks (SGPR);
//   cndmask tree -> this lane's row mask (row = la);
//   reissue adjv for next body (16 contiguous 256B loads — pack's proven shape);
//   S^T = mfma(K, Q): lane holds 4 k-consecutive P values per k-tile ->
//   exp -> ONE ds_write_b64 per k-tile (4 total; was 16 scalar b16) ->
//   pa b128 reads -> PV mfma. No __syncthreads, no staging, no vmcnt asm.
__global__ __launch_bounds__(256, 3) void attn_kernel(const int* __restrict__ adj,
                                                      const ushort* __restrict__ ws,
                                                      ushort* __restrict__ pacc,
                                                      float* __restrict__ pden) {
    __shared__ ushort P[4][16][72];   // per-wave private P staging (9.2KB)

    int bid = blockIdx.x;
    int h = bid & 7, qb = (bid >> 3) & 63, ks = bid >> 9;
    int wave = threadIdx.x >> 6, lane = threadIdx.x & 63;
    int la = lane & 15, lk = lane >> 4;
    int q0w = qb * 64 + wave * 16;

    const ushort* Qh = ws + QF_OFF + (size_t)h * 262144;
    const ushort* Kh = ws + KF_OFF + (size_t)h * 262144;
    const ushort* Vh = ws + VF_OFF + (size_t)h * 262144;
    const int* adjw = adj + (size_t)h * 16777216 + (size_t)q0w * 4096;

    // Q fragments (serve as the B-operand of the swapped QK^T; same fragment structure)
    bf16x8 qa0 = *reinterpret_cast<const bf16x8*>(Qh + ((((size_t)(q0w >> 4)) * 2 + 0) * 64 + lane) * 8);
    bf16x8 qa1 = *reinterpret_cast<const bf16x8*>(Qh + ((((size_t)(q0w >> 4)) * 2 + 1) * 64 + lane) * 8);

    f32x4 acc[4];
#pragma unroll
    for (int r = 0; r < 4; ++r) acc[r] = (f32x4){0.f, 0.f, 0.f, 0.f};
    float den = 0.f;
    int lk4 = lk * 4;

    const f32x4 zero = {0.f, 0.f, 0.f, 0.f};
    int kb0 = ks * 16;

    // prologue: adj loads for body 0 (contiguous: lane l <-> key kb*64+l, row j)
    int adjv[16];
#pragma unroll
    for (int j = 0; j < 16; ++j)
        adjv[j] = __builtin_nontemporal_load(adjw + (size_t)j * 4096 + (size_t)kb0 * 64 + lane);

    for (int it = 0; it < 16; ++it) {
        int kb = kb0 + it;

        // ballots: bit l of mm[j] = adj[row j][kb*64+l]  (loads are one full body old)
        unsigned long long mm[16];
#pragma unroll
        for (int j = 0; j < 16; ++j)
            mm[j] = __ballot(adjv[j] != 0);

        // per-lane row-select (row = la) via cndmask tree
        unsigned long long t8[8], t4[4], t2[2], msel;
#pragma unroll
        for (int i = 0; i < 8; ++i) t8[i] = (la & 1) ? mm[2 * i + 1] : mm[2 * i];
#pragma unroll
        for (int i = 0; i < 4; ++i) t4[i] = (la & 2) ? t8[2 * i + 1] : t8[2 * i];
#pragma unroll
        for (int i = 0; i < 2; ++i) t2[i] = (la & 4) ? t4[2 * i + 1] : t4[2 * i];
        msel = (la & 8) ? t2[1] : t2[0];
        unsigned int mlo = (unsigned int)msel;
        unsigned int mhi = (unsigned int)(msel >> 32);
        __builtin_amdgcn_sched_barrier(0);

        // reissue adj for next body (contiguous 256B x 16; consumed next body top)
        if (it < 15) {
#pragma unroll
            for (int j = 0; j < 16; ++j)
                adjv[j] = __builtin_nontemporal_load(adjw + (size_t)j * 4096 + (size_t)(kb + 1) * 64 + lane);
        }
        __builtin_amdgcn_sched_barrier(0);

        // swapped QK^T: S^T[k][q] = mfma(A=K, B=Q); lane (la,lk) -> q=la, k=kt*16+lk4+r
#pragma unroll
        for (int kt = 0; kt < 4; ++kt) {
            const ushort* kp = Kh + (((size_t)(kb * 4 + kt) * 2) * 64 + lane) * 8;
            bf16x8 kf0 = *reinterpret_cast<const bf16x8*>(kp);
            bf16x8 kf1 = *reinterpret_cast<const bf16x8*>(kp + 512);
            f32x4 s = __builtin_amdgcn_mfma_f32_16x16x32_bf16(kf0, qa0, zero, 0, 0, 0);
            s = __builtin_amdgcn_mfma_f32_16x16x32_bf16(kf1, qa1, s, 0, 0, 0);
            // mask + exp; 4 k-consecutive values -> one b64 write
            unsigned int dw = (kt < 2) ? mlo : mhi;
            int sh = ((kt & 1) << 4) + lk4;
            ushort4 pw;
            float e0 = __expf(((dw >> (sh + 0)) & 1u) ? s[0] : -1e30f);
            float e1 = __expf(((dw >> (sh + 1)) & 1u) ? s[1] : -1e30f);
            float e2 = __expf(((dw >> (sh + 2)) & 1u) ? s[2] : -1e30f);
            float e3 = __expf(((dw >> (sh + 3)) & 1u) ? s[3] : -1e30f);
            den += (e0 + e1) + (e2 + e3);
            pw.x = f2bf(e0); pw.y = f2bf(e1); pw.z = f2bf(e2); pw.w = f2bf(e3);
            *reinterpret_cast<ushort4*>(&P[wave][la][kt * 16 + lk4]) = pw;
        }

        // PV: pa = A-fragment (row q=la, k contiguous) straight from the b64-written P
        bf16x8 pa0 = *reinterpret_cast<const bf16x8*>(&P[wave][la][lk * 8]);
        bf16x8 pa1 = *reinterpret_cast<const bf16x8*>(&P[wave][la][32 + lk * 8]);
#pragma unroll
        for (int dt = 0; dt < 4; ++dt) {
            const ushort* vp = Vh + ((((size_t)kb * 4 + dt) * 2) * 64 + lane) * 8;
            bf16x8 vb0 = *reinterpret_cast<const bf16x8*>(vp);
            bf16x8 vb1 = *reinterpret_cast<const bf16x8*>(vp + 512);
            acc[dt] = __builtin_amdgcn_mfma_f32_16x16x32_bf16(pa0, vb0, acc[dt], 0, 0, 0);
            acc[dt] = __builtin_amdgcn_mfma_f32_16x16x32_bf16(pa1, vb1, acc[dt], 0, 0, 0);
        }
    }

    // den: reduce over the 4 lk groups (lanes ±16, ±32); every lane ends with row la's sum
    den += __shfl_xor(den, 16, 64);
    den += __shfl_xor(den, 32, 64);

    // store bf16 partial acc (D: row q = lk4+reg, col d = dt*16+la — unchanged layout)
    ushort* pa_out = pacc + ((size_t)ks * 8 + h) * 4096 * 64;
#pragma unroll
    for (int dt = 0; dt < 4; ++dt)
#pragma unroll
        for (int r = 0; r < 4; ++r) {
            int qi = q0w + lk4 + r;
            __builtin_nontemporal_store(f2bf(acc[dt][r]), pa_out + (size_t)qi * 64 + dt * 16 + la);
        }
    if (lane < 16) {
        float* pd = pden + ((size_t)ks * 8 + h) * 4096;
        pd[q0w + lane] = den;
    }
}

// ---------------- kernel 3: combine bf16 partials + epilogue ----------------
__global__ __launch_bounds__(256) void combine_kernel(const float* __restrict__ x,
                                                      const ushort* __restrict__ pacc,
                                                      const float* __restrict__ pden,
                                                      float* __restrict__ out) {
    int idx = blockIdx.x * 256 + threadIdx.x;   // 524288 total
    int n = idx >> 7, fq = idx & 127;
    int h = fq >> 4;
    int d4 = (fq & 15) * 4;

    float4 o = make_float4(0.f, 0.f, 0.f, 0.f);
    float den = 0.f;
#pragma unroll
    for (int ksp = 0; ksp < 4; ++ksp) {
        const ushort* pa = pacc + (((size_t)ksp * 8 + h) * 4096 + n) * 64 + d4;
        ushort4 p = *reinterpret_cast<const ushort4*>(pa);
        o.x += bf2f(p.x); o.y += bf2f(p.y); o.z += bf2f(p.z); o.w += bf2f(p.w);
        den += pden[((size_t)ksp * 8 + h) * 4096 + n];
    }
    float4 xv = *reinterpret_cast<const float4*>(x + (size_t)n * 512 + fq * 4);
    float inv = 1.f / den;
    float4 r;
    r.x = o.x * inv + xv.x;
    r.y = o.y * inv + xv.y;
    r.z = o.z * inv + xv.z;
    r.w = o.w * inv + xv.w;
    r.x = (r.x > 0.f) ? r.x : (__expf(r.x) - 1.f);
    r.y = (r.y > 0.f) ? r.y : (__expf(r.y) - 1.f);
    r.z = (r.z > 0.f) ? r.z : (__expf(r.z) - 1.f);
    r.w = (r.w > 0.f) ? r.w : (__expf(r.w) - 1.f);
    *reinterpret_cast<float4*>(out + (size_t)n * 512 + fq * 4) = r;
}

extern "C" void kernel_launch(void* const* d_in, const int* in_sizes, int n_in,
                              void* d_out, int out_size, void* d_ws, size_t ws_size,
                              hipStream_t stream) {
    const float* x  = (const float*)d_in[0];
    const float* wq = (const float*)d_in[1];
    const float* wk = (const float*)d_in[2];
    const float* wv = (const float*)d_in[3];
    const int*   adj = (const int*)d_in[4];
    float* out = (float*)d_out;
    ushort* ws = (ushort*)d_ws;
    ushort* pacc = ws + PACC_OFF;
    float* pden = (float*)(ws + PDEN_USHORT_OFF);

    cvt_kernel<<<2816, 256, 0, stream>>>(x, wq, wk, wv, ws);
    qkv_kernel<<<dim3(24, 64), 256, 0, stream>>>(ws);
    attn_kernel<<<2048, 256, 0, stream>>>(adj, ws, pacc, pden);
    combine_kernel<<<2048, 256, 0, stream>>>(x, pacc, pden, out);
}

// Round 15
// 247.897 us; speedup vs baseline: 2.7056x; 2.7056x over previous
//
#include <hip/hip_runtime.h>
#include <hip/hip_bf16.h>

#define NN 4096
#define FF 512
#define NH 8
#define DH 64

typedef __attribute__((ext_vector_type(8))) short bf16x8;
typedef __attribute__((ext_vector_type(4))) float f32x4;

// ws layout in ushort elements:
//  X_BF  [4096][512]                    @ 0
//  W_BF  [3][512][512]                  @ 2097152   (Wq pre-scaled by 1/sqrt(512))
//  QF    [8][256 blk][2 half][64 ln][8] @ 2883584   (MFMA fragment order)
//  KF    [8][256 blk][2 half][64 ln][8] @ 4980736   (MFMA fragment order)
//  VF    [8][64 kb][4 dt][2 hf][64][8]  @ 7077888   (MFMA B-fragment order, d-major)
//  PACC  bf16 [4 ks][8 h][4096][64]     @ 9175040   (8388608 ushorts)
//  PDEN  f32  [4 ks][8 h][4096]         @ 17563648  (262144 ushorts)
#define X_OFF  0
#define W_OFF  2097152
#define QF_OFF 2883584
#define KF_OFF 4980736
#define VF_OFF 7077888
#define PACC_OFF 9175040
#define PDEN_USHORT_OFF 17563648

__device__ __forceinline__ ushort f2bf(float f) {
    __hip_bfloat16 h = __float2bfloat16(f);
    return __builtin_bit_cast(ushort, h);
}
__device__ __forceinline__ float bf2f(ushort u) {
    unsigned int v = ((unsigned int)u) << 16;
    return __builtin_bit_cast(float, v);
}

// ---------------- kernel 0: f32 -> bf16 convert (x, Wq*scale, Wk, Wv) ----------------
__global__ __launch_bounds__(256) void cvt_kernel(const float* __restrict__ x,
                                                  const float* __restrict__ wq,
                                                  const float* __restrict__ wk,
                                                  const float* __restrict__ wv,
                                                  ushort* __restrict__ ws) {
    int i = blockIdx.x * 256 + threadIdx.x;
    int base = i * 4;
    const float* src;
    int off;
    float sc = 1.f;
    if (base < 2097152) { src = x; off = base; }
    else {
        int t = base - 2097152;
        int m = t >> 18;
        src = (m == 0) ? wq : ((m == 1) ? wk : wv);
        if (m == 0) sc = 0.044194173824159216f;   // 1/sqrt(512) folded into Wq
        off = t & 262143;
    }
    float4 v = *reinterpret_cast<const float4*>(src + off);
    ushort4 o;
    o.x = f2bf(v.x * sc); o.y = f2bf(v.y * sc); o.z = f2bf(v.z * sc); o.w = f2bf(v.w * sc);
    *reinterpret_cast<ushort4*>(ws + base) = o;
}

// ---------------- kernel 1: QKV projection, outputs in MFMA-fragment order ----------------
__global__ __launch_bounds__(256) void qkv_kernel(ushort* __restrict__ ws) {
    int bx = blockIdx.x;
    int mat = bx >> 3;          // 0=Q,1=K,2=V
    int fb  = bx & 7;           // head
    int mb  = blockIdx.y;
    int wave = threadIdx.x >> 6, lane = threadIdx.x & 63;
    int la = lane & 15, lk = lane >> 4;

    int m_base = mb * 64 + wave * 16;
    int f_base = fb * 64;

    const ushort* xb = ws + X_OFF;
    const ushort* wb = ws + W_OFF + mat * 262144;

    f32x4 acc[4];
#pragma unroll
    for (int t = 0; t < 4; ++t) acc[t] = (f32x4){0.f, 0.f, 0.f, 0.f};

#pragma unroll 4
    for (int k0 = 0; k0 < 512; k0 += 32) {
        bf16x8 a = *reinterpret_cast<const bf16x8*>(xb + (size_t)(m_base + la) * 512 + k0 + lk * 8);
#pragma unroll
        for (int ft = 0; ft < 4; ++ft) {
            bf16x8 b = *reinterpret_cast<const bf16x8*>(wb + (size_t)(f_base + ft * 16 + la) * 512 + k0 + lk * 8);
            acc[ft] = __builtin_amdgcn_mfma_f32_16x16x32_bf16(a, b, acc[ft], 0, 0, 0);
        }
    }

#pragma unroll
    for (int ft = 0; ft < 4; ++ft) {
#pragma unroll
        for (int r = 0; r < 4; ++r) {
            int n = m_base + lk * 4 + r;
            int d = ft * 16 + la;          // head-local feature
            ushort v = f2bf(acc[ft][r]);
            if (mat < 2) {
                ushort* base = ws + (mat == 0 ? QF_OFF : KF_OFF) + (size_t)fb * 262144;
                int blk = n >> 4, rr = n & 15;
                int half = d >> 5, lkk = (d >> 3) & 3, e = d & 7;
                base[(((size_t)blk * 2 + half) * 64 + lkk * 16 + rr) * 8 + e] = v;
            } else {
                ushort* base = ws + VF_OFF + (size_t)fb * 262144;
                int kb64 = n >> 6, kc = n & 63;
                int hf = kc >> 5, lkv = (kc >> 3) & 3, ev = kc & 7;
                int dt = d >> 4, lav = d & 15;
                base[((((size_t)kb64 * 4 + dt) * 2 + hf) * 64 + lkv * 16 + lav) * 8 + ev] = v;
            }
        }
    }
}

// ---------------- kernel 2: fused attention — swapped QK^T, low-pressure ballot masks --
// grid 2048: h = bid&7 (XCD-pinned), qb = (bid>>3)&63, ks = bid>>9 (0..3).
// 4 waves x 16 q-rows; 16 bodies of 64 keys. Per body:
//   16 ballots (adjv loaded one body ago, pack's contiguous 256B shape) consumed
//   IMMEDIATELY into two u32 accumulators (mlo/mhi) via (la==j) cndmask — per-lane
//   mask state = 2 VGPRs, ballots stay in SGPRs (this is the R14 spill fix);
//   reissue adjv; swapped QK^T (verified R14): lane q=la, k=kt*16+lk*4+r;
//   fused bit-mask+exp -> ONE ds_write_b64 per kt; b128 pa reads -> PV mfma.
// No __syncthreads, no staging, no vmcnt asm. ~100 VGPR -> (256,4), 16 waves/CU.
__global__ __launch_bounds__(256, 4) void attn_kernel(const int* __restrict__ adj,
                                                      const ushort* __restrict__ ws,
                                                      ushort* __restrict__ pacc,
                                                      float* __restrict__ pden) {
    __shared__ ushort P[4][16][72];   // per-wave private P staging (9.2KB)

    int bid = blockIdx.x;
    int h = bid & 7, qb = (bid >> 3) & 63, ks = bid >> 9;
    int wave = threadIdx.x >> 6, lane = threadIdx.x & 63;
    int la = lane & 15, lk = lane >> 4;
    int q0w = qb * 64 + wave * 16;
    int lk4 = lk * 4;

    const ushort* Qh = ws + QF_OFF + (size_t)h * 262144;
    const ushort* Kh = ws + KF_OFF + (size_t)h * 262144;
    const ushort* Vh = ws + VF_OFF + (size_t)h * 262144;
    const int* adjw = adj + (size_t)h * 16777216 + (size_t)q0w * 4096;

    // Q fragments (B-operand of the swapped QK^T)
    bf16x8 qa0 = *reinterpret_cast<const bf16x8*>(Qh + ((((size_t)(q0w >> 4)) * 2 + 0) * 64 + lane) * 8);
    bf16x8 qa1 = *reinterpret_cast<const bf16x8*>(Qh + ((((size_t)(q0w >> 4)) * 2 + 1) * 64 + lane) * 8);

    f32x4 acc[4];
#pragma unroll
    for (int r = 0; r < 4; ++r) acc[r] = (f32x4){0.f, 0.f, 0.f, 0.f};
    float den = 0.f;

    const f32x4 zero = {0.f, 0.f, 0.f, 0.f};
    int kb0 = ks * 16;

    // prologue: adj loads for body 0 (contiguous: lane l <-> key kb*64+l, row j)
    int adjv[16];
#pragma unroll
    for (int j = 0; j < 16; ++j)
        adjv[j] = __builtin_nontemporal_load(adjw + (size_t)j * 4096 + (size_t)kb0 * 64 + lane);

    for (int it = 0; it < 16; ++it) {
        int kb = kb0 + it;

        // ballots consumed immediately: lane keeps ONLY row la's mask (2 VGPRs)
        unsigned int mlo = 0u, mhi = 0u;
#pragma unroll
        for (int j = 0; j < 16; ++j) {
            unsigned long long mj = __ballot(adjv[j] != 0);   // wave-uniform (SGPR pair)
            mlo = (la == j) ? (unsigned int)mj : mlo;
            mhi = (la == j) ? (unsigned int)(mj >> 32) : mhi;
        }
        __builtin_amdgcn_sched_barrier(0);

        // reissue adj for next body (contiguous 256B x 16; consumed next body top)
        if (it < 15) {
#pragma unroll
            for (int j = 0; j < 16; ++j)
                adjv[j] = __builtin_nontemporal_load(adjw + (size_t)j * 4096 + (size_t)(kb + 1) * 64 + lane);
        }
        __builtin_amdgcn_sched_barrier(0);

        // swapped QK^T: S^T = mfma(A=K, B=Q); lane (la,lk) -> q=la, k=kt*16+lk4+r
#pragma unroll
        for (int kt = 0; kt < 4; ++kt) {
            const ushort* kp = Kh + (((size_t)(kb * 4 + kt) * 2) * 64 + lane) * 8;
            bf16x8 kf0 = *reinterpret_cast<const bf16x8*>(kp);
            bf16x8 kf1 = *reinterpret_cast<const bf16x8*>(kp + 512);
            f32x4 s = __builtin_amdgcn_mfma_f32_16x16x32_bf16(kf0, qa0, zero, 0, 0, 0);
            s = __builtin_amdgcn_mfma_f32_16x16x32_bf16(kf1, qa1, s, 0, 0, 0);
            // fused bit-mask + exp; 4 k-consecutive values -> one b64 write
            unsigned int dw = (kt < 2) ? mlo : mhi;
            int sh = ((kt & 1) << 4) + lk4;
            ushort4 pw;
            float e0 = __expf(((dw >> (sh + 0)) & 1u) ? s[0] : -1e30f);
            float e1 = __expf(((dw >> (sh + 1)) & 1u) ? s[1] : -1e30f);
            float e2 = __expf(((dw >> (sh + 2)) & 1u) ? s[2] : -1e30f);
            float e3 = __expf(((dw >> (sh + 3)) & 1u) ? s[3] : -1e30f);
            den += (e0 + e1) + (e2 + e3);
            pw.x = f2bf(e0); pw.y = f2bf(e1); pw.z = f2bf(e2); pw.w = f2bf(e3);
            *reinterpret_cast<ushort4*>(&P[wave][la][kt * 16 + lk4]) = pw;
        }

        // PV: pa = A-fragment (row q=la, k contiguous) from the b64-written P
        bf16x8 pa0 = *reinterpret_cast<const bf16x8*>(&P[wave][la][lk * 8]);
        bf16x8 pa1 = *reinterpret_cast<const bf16x8*>(&P[wave][la][32 + lk * 8]);
#pragma unroll
        for (int dt = 0; dt < 4; ++dt) {
            const ushort* vp = Vh + ((((size_t)kb * 4 + dt) * 2) * 64 + lane) * 8;
            bf16x8 vb0 = *reinterpret_cast<const bf16x8*>(vp);
            bf16x8 vb1 = *reinterpret_cast<const bf16x8*>(vp + 512);
            acc[dt] = __builtin_amdgcn_mfma_f32_16x16x32_bf16(pa0, vb0, acc[dt], 0, 0, 0);
            acc[dt] = __builtin_amdgcn_mfma_f32_16x16x32_bf16(pa1, vb1, acc[dt], 0, 0, 0);
        }
    }

    // den: reduce over the 4 lk groups; every lane ends with row la's full sum
    den += __shfl_xor(den, 16, 64);
    den += __shfl_xor(den, 32, 64);

    // store bf16 partial acc (D row q = lk4+reg, col d = dt*16+la — R14-verified layout)
    ushort* pa_out = pacc + ((size_t)ks * 8 + h) * 4096 * 64;
#pragma unroll
    for (int dt = 0; dt < 4; ++dt)
#pragma unroll
        for (int r = 0; r < 4; ++r) {
            int qi = q0w + lk4 + r;
            __builtin_nontemporal_store(f2bf(acc[dt][r]), pa_out + (size_t)qi * 64 + dt * 16 + la);
        }
    if (lane < 16) {
        float* pd = pden + ((size_t)ks * 8 + h) * 4096;
        pd[q0w + lane] = den;
    }
}

// ---------------- kernel 3: combine bf16 partials + epilogue ----------------
__global__ __launch_bounds__(256) void combine_kernel(const float* __restrict__ x,
                                                      const ushort* __restrict__ pacc,
                                                      const float* __restrict__ pden,
                                                      float* __restrict__ out) {
    int idx = blockIdx.x * 256 + threadIdx.x;   // 524288 total
    int n = idx >> 7, fq = idx & 127;
    int h = fq >> 4;
    int d4 = (fq & 15) * 4;

    float4 o = make_float4(0.f, 0.f, 0.f, 0.f);
    float den = 0.f;
#pragma unroll
    for (int ksp = 0; ksp < 4; ++ksp) {
        const ushort* pa = pacc + (((size_t)ksp * 8 + h) * 4096 + n) * 64 + d4;
        ushort4 p = *reinterpret_cast<const ushort4*>(pa);
        o.x += bf2f(p.x); o.y += bf2f(p.y); o.z += bf2f(p.z); o.w += bf2f(p.w);
        den += pden[((size_t)ksp * 8 + h) * 4096 + n];
    }
    float4 xv = *reinterpret_cast<const float4*>(x + (size_t)n * 512 + fq * 4);
    float inv = 1.f / den;
    float4 r;
    r.x = o.x * inv + xv.x;
    r.y = o.y * inv + xv.y;
    r.z = o.z * inv + xv.z;
    r.w = o.w * inv + xv.w;
    r.x = (r.x > 0.f) ? r.x : (__expf(r.x) - 1.f);
    r.y = (r.y > 0.f) ? r.y : (__expf(r.y) - 1.f);
    r.z = (r.z > 0.f) ? r.z : (__expf(r.z) - 1.f);
    r.w = (r.w > 0.f) ? r.w : (__expf(r.w) - 1.f);
    *reinterpret_cast<float4*>(out + (size_t)n * 512 + fq * 4) = r;
}

extern "C" void kernel_launch(void* const* d_in, const int* in_sizes, int n_in,
                              void* d_out, int out_size, void* d_ws, size_t ws_size,
                              hipStream_t stream) {
    const float* x  = (const float*)d_in[0];
    const float* wq = (const float*)d_in[1];
    const float* wk = (const float*)d_in[2];
    const float* wv = (const float*)d_in[3];
    const int*   adj = (const int*)d_in[4];
    float* out = (float*)d_out;
    ushort* ws = (ushort*)d_ws;
    ushort* pacc = ws + PACC_OFF;
    float* pden = (float*)(ws + PDEN_USHORT_OFF);

    cvt_kernel<<<2816, 256, 0, stream>>>(x, wq, wk, wv, ws);
    qkv_kernel<<<dim3(24, 64), 256, 0, stream>>>(ws);
    attn_kernel<<<2048, 256, 0, stream>>>(adj, ws, pacc, pden);
    combine_kernel<<<2048, 256, 0, stream>>>(x, pacc, pden, out);
}

// Round 16
// 226.847 us; speedup vs baseline: 2.9566x; 1.0928x over previous
//
#include <hip/hip_runtime.h>
#include <hip/hip_bf16.h>

#define NN 4096
#define FF 512
#define NH 8
#define DH 64

typedef __attribute__((ext_vector_type(8))) short bf16x8;
typedef __attribute__((ext_vector_type(4))) float f32x4;

// ws layout in ushort elements:
//  X_BF  [4096][512]                    @ 0
//  W_BF  [3][512][512]                  @ 2097152   (Wq pre-scaled by 1/sqrt(512))
//  QF    [8][256 blk][2 half][64 ln][8] @ 2883584   (MFMA fragment order)
//  KF    [8][256 blk][2 half][64 ln][8] @ 4980736   (MFMA fragment order)
//  VF    [8][64 kb][4 dt][2 hf][64][8]  @ 7077888   (MFMA B-fragment order, d-major)
//  PACC  bf16 [4 ks][8 h][4096][64]     @ 9175040   (8388608 ushorts)
//  PDEN  f32  [4 ks][8 h][4096]         @ 17563648  (262144 ushorts)
//  PK    u32  [8*4096 rows][128]        @ 17825792  (bit c of dword j = adj!=0 @ col 32j+c)
#define X_OFF  0
#define W_OFF  2097152
#define QF_OFF 2883584
#define KF_OFF 4980736
#define VF_OFF 7077888
#define PACC_OFF 9175040
#define PDEN_USHORT_OFF 17563648
#define PK_USHORT_OFF 17825792

__device__ __forceinline__ ushort f2bf(float f) {
    __hip_bfloat16 h = __float2bfloat16(f);
    return __builtin_bit_cast(ushort, h);
}
__device__ __forceinline__ float bf2f(ushort u) {
    unsigned int v = ((unsigned int)u) << 16;
    return __builtin_bit_cast(float, v);
}

// ---------------- kernel 0: f32 -> bf16 convert (x, Wq*scale, Wk, Wv) ----------------
__global__ __launch_bounds__(256) void cvt_kernel(const float* __restrict__ x,
                                                  const float* __restrict__ wq,
                                                  const float* __restrict__ wk,
                                                  const float* __restrict__ wv,
                                                  ushort* __restrict__ ws) {
    int i = blockIdx.x * 256 + threadIdx.x;
    int base = i * 4;
    const float* src;
    int off;
    float sc = 1.f;
    if (base < 2097152) { src = x; off = base; }
    else {
        int t = base - 2097152;
        int m = t >> 18;
        src = (m == 0) ? wq : ((m == 1) ? wk : wv);
        if (m == 0) sc = 0.044194173824159216f;   // 1/sqrt(512) folded into Wq
        off = t & 262143;
    }
    float4 v = *reinterpret_cast<const float4*>(src + off);
    ushort4 o;
    o.x = f2bf(v.x * sc); o.y = f2bf(v.y * sc); o.z = f2bf(v.z * sc); o.w = f2bf(v.w * sc);
    *reinterpret_cast<ushort4*>(ws + base) = o;
}

// ---------------- kernel 1: pack (8192 blocks) || qkv (1536 blocks), one launch --------
// pack: proven-BW adj streamer (contiguous 256B/instr + __ballot 64:1).
// qkv: projections into MFMA-fragment order; rides inside pack's memory time.
__global__ __launch_bounds__(256) void packqkv_kernel(const int* __restrict__ adj,
                                                      unsigned int* __restrict__ pk,
                                                      ushort* __restrict__ ws) {
    int bid = blockIdx.x;
    int wave = threadIdx.x >> 6, lane = threadIdx.x & 63;

    if (bid < 8192) {
        int row = bid * 4 + wave;
        const int* ar = adj + (size_t)row * 4096;
        unsigned long long* outp = reinterpret_cast<unsigned long long*>(pk + (size_t)row * 128);
        for (int it = 0; it < 64; it += 4) {
            int v0 = __builtin_nontemporal_load(ar + (it + 0) * 64 + lane);
            int v1 = __builtin_nontemporal_load(ar + (it + 1) * 64 + lane);
            int v2 = __builtin_nontemporal_load(ar + (it + 2) * 64 + lane);
            int v3 = __builtin_nontemporal_load(ar + (it + 3) * 64 + lane);
            unsigned long long b0 = __ballot(v0 != 0);
            unsigned long long b1 = __ballot(v1 != 0);
            unsigned long long b2 = __ballot(v2 != 0);
            unsigned long long b3 = __ballot(v3 != 0);
            if (lane == 0) {
                outp[it + 0] = b0;
                outp[it + 1] = b1;
                outp[it + 2] = b2;
                outp[it + 3] = b3;
            }
        }
        return;
    }

    int q = bid - 8192;            // 0..1535
    int mat = q >> 9;              // 0=Q,1=K,2=V
    int rem = q & 511;
    int fb = rem & 7;              // head
    int mb = rem >> 3;             // 0..63
    int la = lane & 15, lk = lane >> 4;

    int m_base = mb * 64 + wave * 16;
    int f_base = fb * 64;

    const ushort* xb = ws + X_OFF;
    const ushort* wb = ws + W_OFF + mat * 262144;

    f32x4 acc[4];
#pragma unroll
    for (int t = 0; t < 4; ++t) acc[t] = (f32x4){0.f, 0.f, 0.f, 0.f};

#pragma unroll 4
    for (int k0 = 0; k0 < 512; k0 += 32) {
        bf16x8 a = *reinterpret_cast<const bf16x8*>(xb + (size_t)(m_base + la) * 512 + k0 + lk * 8);
#pragma unroll
        for (int ft = 0; ft < 4; ++ft) {
            bf16x8 b = *reinterpret_cast<const bf16x8*>(wb + (size_t)(f_base + ft * 16 + la) * 512 + k0 + lk * 8);
            acc[ft] = __builtin_amdgcn_mfma_f32_16x16x32_bf16(a, b, acc[ft], 0, 0, 0);
        }
    }

#pragma unroll
    for (int ft = 0; ft < 4; ++ft) {
#pragma unroll
        for (int r = 0; r < 4; ++r) {
            int n = m_base + lk * 4 + r;
            int d = ft * 16 + la;          // head-local feature
            ushort v = f2bf(acc[ft][r]);
            if (mat < 2) {
                ushort* base = ws + (mat == 0 ? QF_OFF : KF_OFF) + (size_t)fb * 262144;
                int blk = n >> 4, rr = n & 15;
                int half = d >> 5, lkk = (d >> 3) & 3, e = d & 7;
                base[(((size_t)blk * 2 + half) * 64 + lkk * 16 + rr) * 8 + e] = v;
            } else {
                ushort* base = ws + VF_OFF + (size_t)fb * 262144;
                int kb64 = n >> 6, kc = n & 63;
                int hf = kc >> 5, lkv = (kc >> 3) & 3, ev = kc & 7;
                int dt = d >> 4, lav = d & 15;
                base[((((size_t)kb64 * 4 + dt) * 2 + hf) * 64 + lkv * 16 + lav) * 8 + ev] = v;
            }
        }
    }
}

// ---------------- kernel 2: attention — LDS-staged K/V + pk masks + swapped QK^T -------
// grid 2048: h = bid&7 (XCD-pinned), qb = (bid>>3)&63, ks = bid>>9 (0..3).
// 4 waves x 16 q-rows; 16 bodies of 64 keys. L2 traffic: K/V staged ONCE per block
// (1 GB total vs 4.2 GB per-wave re-reads — the R13 limiter). Per body:
//   [vmcnt(0): only stage(t), issued one body ago, is outstanding; barrier] ->
//   STAGE(t+1) -> mask = ONE uint2/lane (row la, L2-broadcast; latency hides under QK)
//   -> swapped QK^T from kbuf -> fused bit-mask+exp -> b64 P-write -> PV from vbuf.
__global__ __launch_bounds__(256, 3) void attn_kernel(const unsigned int* __restrict__ pk,
                                                      const ushort* __restrict__ ws,
                                                      ushort* __restrict__ pacc,
                                                      float* __restrict__ pden) {
    __shared__ ushort kbuf[2][8][512];   // 16KB
    __shared__ ushort vbuf[2][8][512];   // 16KB
    __shared__ ushort P[4][16][72];      // 9.2KB per-wave P staging

    int bid = blockIdx.x;
    int h = bid & 7, qb = (bid >> 3) & 63, ks = bid >> 9;
    int wave = threadIdx.x >> 6, lane = threadIdx.x & 63;
    int la = lane & 15, lk = lane >> 4;
    int q0w = qb * 64 + wave * 16;
    int lk4 = lk * 4;

    const ushort* Qh = ws + QF_OFF + (size_t)h * 262144;
    const ushort* Kh = ws + KF_OFF + (size_t)h * 262144;
    const ushort* Vh = ws + VF_OFF + (size_t)h * 262144;
    const unsigned int* mrow = pk + ((size_t)h * 4096 + q0w + la) * 128;   // this lane's q-row

    // Q fragments (B-operand of swapped QK^T)
    bf16x8 qa0 = *reinterpret_cast<const bf16x8*>(Qh + ((((size_t)(q0w >> 4)) * 2 + 0) * 64 + lane) * 8);
    bf16x8 qa1 = *reinterpret_cast<const bf16x8*>(Qh + ((((size_t)(q0w >> 4)) * 2 + 1) * 64 + lane) * 8);

    f32x4 acc[4];
#pragma unroll
    for (int r = 0; r < 4; ++r) acc[r] = (f32x4){0.f, 0.f, 0.f, 0.f};
    float den = 0.f;

    const f32x4 zero = {0.f, 0.f, 0.f, 0.f};
    int kb0 = ks * 16;

    // stage body 0 (K tiles by waves 0-1, V tiles by waves 2-3; 16B/lane each op)
#define STAGE(BUF, KB)                                                                     \
    {                                                                                      \
        const ushort* sbase_ = (wave < 2) ? Kh : Vh;                                       \
        ushort(*dbuf_)[512] = (wave < 2) ? kbuf[BUF] : vbuf[BUF];                          \
        int t0_ = (wave & 1) * 4;                                                          \
        _Pragma("unroll")                                                                  \
        for (int t_ = 0; t_ < 4; ++t_) {                                                   \
            int tile_ = t0_ + t_;                                                          \
            const ushort* src_ = sbase_ +                                                  \
                (((size_t)(KB) * 4 + (tile_ >> 1)) * 2 + (tile_ & 1)) * 512 + lane * 8;    \
            __builtin_amdgcn_global_load_lds(                                              \
                (const __attribute__((address_space(1))) unsigned int*)src_,               \
                (__attribute__((address_space(3))) unsigned int*)&dbuf_[tile_][0],         \
                16, 0, 0);                                                                 \
        }                                                                                  \
    }

    STAGE(0, kb0)

    for (int it = 0; it < 16; ++it) {
        int kb = kb0 + it;
        int cur = it & 1;

        // only stage(t) (issued one body ago) is outstanding here -> free drain
        asm volatile("s_waitcnt vmcnt(0)" ::: "memory");
        __builtin_amdgcn_s_barrier();

        if (it < 15) STAGE(cur ^ 1, kb + 1)

        // this body's mask: one uint2 per lane (row q0w+la), L2 broadcast across lk
        uint2 mk = *reinterpret_cast<const uint2*>(mrow + kb * 2);

        // swapped QK^T from LDS: S^T = mfma(A=K, B=Q); lane (la,lk) -> q=la, k=kt*16+lk4+r
#pragma unroll
        for (int kt = 0; kt < 4; ++kt) {
            bf16x8 kf0 = *reinterpret_cast<const bf16x8*>(&kbuf[cur][kt * 2 + 0][lane * 8]);
            bf16x8 kf1 = *reinterpret_cast<const bf16x8*>(&kbuf[cur][kt * 2 + 1][lane * 8]);
            f32x4 s = __builtin_amdgcn_mfma_f32_16x16x32_bf16(kf0, qa0, zero, 0, 0, 0);
            s = __builtin_amdgcn_mfma_f32_16x16x32_bf16(kf1, qa1, s, 0, 0, 0);
            // fused bit-mask + exp; 4 k-consecutive values -> one b64 write
            unsigned int dw = (kt < 2) ? mk.x : mk.y;
            int sh = ((kt & 1) << 4) + lk4;
            ushort4 pw;
            float e0 = __expf(((dw >> (sh + 0)) & 1u) ? s[0] : -1e30f);
            float e1 = __expf(((dw >> (sh + 1)) & 1u) ? s[1] : -1e30f);
            float e2 = __expf(((dw >> (sh + 2)) & 1u) ? s[2] : -1e30f);
            float e3 = __expf(((dw >> (sh + 3)) & 1u) ? s[3] : -1e30f);
            den += (e0 + e1) + (e2 + e3);
            pw.x = f2bf(e0); pw.y = f2bf(e1); pw.z = f2bf(e2); pw.w = f2bf(e3);
            *reinterpret_cast<ushort4*>(&P[wave][la][kt * 16 + lk4]) = pw;
        }

        // PV: pa = A-fragment (row q=la, k contiguous) from P; V from LDS
        bf16x8 pa0 = *reinterpret_cast<const bf16x8*>(&P[wave][la][lk * 8]);
        bf16x8 pa1 = *reinterpret_cast<const bf16x8*>(&P[wave][la][32 + lk * 8]);
#pragma unroll
        for (int dt = 0; dt < 4; ++dt) {
            bf16x8 vb0 = *reinterpret_cast<const bf16x8*>(&vbuf[cur][dt * 2 + 0][lane * 8]);
            bf16x8 vb1 = *reinterpret_cast<const bf16x8*>(&vbuf[cur][dt * 2 + 1][lane * 8]);
            acc[dt] = __builtin_amdgcn_mfma_f32_16x16x32_bf16(pa0, vb0, acc[dt], 0, 0, 0);
            acc[dt] = __builtin_amdgcn_mfma_f32_16x16x32_bf16(pa1, vb1, acc[dt], 0, 0, 0);
        }
    }

    // den: reduce over the 4 lk groups; every lane ends with row la's full sum
    den += __shfl_xor(den, 16, 64);
    den += __shfl_xor(den, 32, 64);

    // store bf16 partial acc (D row q = lk4+r, col d = dt*16+la — verified layout)
    ushort* pa_out = pacc + ((size_t)ks * 8 + h) * 4096 * 64;
#pragma unroll
    for (int dt = 0; dt < 4; ++dt)
#pragma unroll
        for (int r = 0; r < 4; ++r) {
            int qi = q0w + lk4 + r;
            __builtin_nontemporal_store(f2bf(acc[dt][r]), pa_out + (size_t)qi * 64 + dt * 16 + la);
        }
    if (lane < 16) {
        float* pd = pden + ((size_t)ks * 8 + h) * 4096;
        pd[q0w + lane] = den;
    }
#undef STAGE
}

// ---------------- kernel 3: combine bf16 partials + epilogue ----------------
__global__ __launch_bounds__(256) void combine_kernel(const float* __restrict__ x,
                                                      const ushort* __restrict__ pacc,
                                                      const float* __restrict__ pden,
                                                      float* __restrict__ out) {
    int idx = blockIdx.x * 256 + threadIdx.x;   // 524288 total
    int n = idx >> 7, fq = idx & 127;
    int h = fq >> 4;
    int d4 = (fq & 15) * 4;

    float4 o = make_float4(0.f, 0.f, 0.f, 0.f);
    float den = 0.f;
#pragma unroll
    for (int ksp = 0; ksp < 4; ++ksp) {
        const ushort* pa = pacc + (((size_t)ksp * 8 + h) * 4096 + n) * 64 + d4;
        ushort4 p = *reinterpret_cast<const ushort4*>(pa);
        o.x += bf2f(p.x); o.y += bf2f(p.y); o.z += bf2f(p.z); o.w += bf2f(p.w);
        den += pden[((size_t)ksp * 8 + h) * 4096 + n];
    }
    float4 xv = *reinterpret_cast<const float4*>(x + (size_t)n * 512 + fq * 4);
    float inv = 1.f / den;
    float4 r;
    r.x = o.x * inv + xv.x;
    r.y = o.y * inv + xv.y;
    r.z = o.z * inv + xv.z;
    r.w = o.w * inv + xv.w;
    r.x = (r.x > 0.f) ? r.x : (__expf(r.x) - 1.f);
    r.y = (r.y > 0.f) ? r.y : (__expf(r.y) - 1.f);
    r.z = (r.z > 0.f) ? r.z : (__expf(r.z) - 1.f);
    r.w = (r.w > 0.f) ? r.w : (__expf(r.w) - 1.f);
    *reinterpret_cast<float4*>(out + (size_t)n * 512 + fq * 4) = r;
}

extern "C" void kernel_launch(void* const* d_in, const int* in_sizes, int n_in,
                              void* d_out, int out_size, void* d_ws, size_t ws_size,
                              hipStream_t stream) {
    const float* x  = (const float*)d_in[0];
    const float* wq = (const float*)d_in[1];
    const float* wk = (const float*)d_in[2];
    const float* wv = (const float*)d_in[3];
    const int*   adj = (const int*)d_in[4];
    float* out = (float*)d_out;
    ushort* ws = (ushort*)d_ws;
    ushort* pacc = ws + PACC_OFF;
    float* pden = (float*)(ws + PDEN_USHORT_OFF);
    unsigned int* pk = (unsigned int*)(ws + PK_USHORT_OFF);

    cvt_kernel<<<2816, 256, 0, stream>>>(x, wq, wk, wv, ws);
    packqkv_kernel<<<9728, 256, 0, stream>>>(adj, pk, ws);
    attn_kernel<<<2048, 256, 0, stream>>>(pk, ws, pacc, pden);
    combine_kernel<<<2048, 256, 0, stream>>>(x, pacc, pden, out);
}

// Round 18
// 218.104 us; speedup vs baseline: 3.0752x; 1.0401x over previous
//
#include <hip/hip_runtime.h>
#include <hip/hip_bf16.h>

#define NN 4096
#define FF 512
#define NH 8
#define DH 64

typedef __attribute__((ext_vector_type(8))) short bf16x8;
typedef __attribute__((ext_vector_type(4))) float f32x4;

// ws layout in ushort elements:
//  X_BF  [4096][512]                    @ 0
//  W_BF  [3][512][512]                  @ 2097152   (Wq pre-scaled by 1/sqrt(512))
//  QF    [8][256 blk][2 half][64 ln][8] @ 2883584   (MFMA fragment order)
//  KF    [8][256 blk][2 half][64 ln][8] @ 4980736   (MFMA fragment order)
//  VF    [8][64 kb][4 dt][2 hf][64][8]  @ 7077888   (MFMA B-fragment order, d-major)
//  PACC  bf16 [3 ks][8 h][4096][64]     @ 9175040   (6291456 ushorts used)
//  PDEN  f32  [3 ks][8 h][4096]         @ 17563648  (196608 ushorts used)
//  PK    u32  [8*4096 rows][128]        @ 17825792  (bit c of dword j = adj!=0 @ col 32j+c)
#define X_OFF  0
#define W_OFF  2097152
#define QF_OFF 2883584
#define KF_OFF 4980736
#define VF_OFF 7077888
#define PACC_OFF 9175040
#define PDEN_USHORT_OFF 17563648
#define PK_USHORT_OFF 17825792

__device__ __forceinline__ ushort f2bf(float f) {
    __hip_bfloat16 h = __float2bfloat16(f);
    return __builtin_bit_cast(ushort, h);
}
__device__ __forceinline__ float bf2f(ushort u) {
    unsigned int v = ((unsigned int)u) << 16;
    return __builtin_bit_cast(float, v);
}

// ---------------- kernel 0: f32 -> bf16 convert (x, Wq*scale, Wk, Wv) ----------------
__global__ __launch_bounds__(256) void cvt_kernel(const float* __restrict__ x,
                                                  const float* __restrict__ wq,
                                                  const float* __restrict__ wk,
                                                  const float* __restrict__ wv,
                                                  ushort* __restrict__ ws) {
    int i = blockIdx.x * 256 + threadIdx.x;
    int base = i * 4;
    const float* src;
    int off;
    float sc = 1.f;
    if (base < 2097152) { src = x; off = base; }
    else {
        int t = base - 2097152;
        int m = t >> 18;
        src = (m == 0) ? wq : ((m == 1) ? wk : wv);
        if (m == 0) sc = 0.044194173824159216f;   // 1/sqrt(512) folded into Wq
        off = t & 262143;
    }
    float4 v = *reinterpret_cast<const float4*>(src + off);
    ushort4 o;
    o.x = f2bf(v.x * sc); o.y = f2bf(v.y * sc); o.z = f2bf(v.z * sc); o.w = f2bf(v.w * sc);
    *reinterpret_cast<ushort4*>(ws + base) = o;
}

// ---------------- kernel 1: pack (8192 blocks) || qkv (1536 blocks), one launch --------
__global__ __launch_bounds__(256) void packqkv_kernel(const int* __restrict__ adj,
                                                      unsigned int* __restrict__ pk,
                                                      ushort* __restrict__ ws) {
    int bid = blockIdx.x;
    int wave = threadIdx.x >> 6, lane = threadIdx.x & 63;

    if (bid < 8192) {
        int row = bid * 4 + wave;
        const int* ar = adj + (size_t)row * 4096;
        unsigned long long* outp = reinterpret_cast<unsigned long long*>(pk + (size_t)row * 128);
        for (int it = 0; it < 64; it += 4) {
            int v0 = __builtin_nontemporal_load(ar + (it + 0) * 64 + lane);
            int v1 = __builtin_nontemporal_load(ar + (it + 1) * 64 + lane);
            int v2 = __builtin_nontemporal_load(ar + (it + 2) * 64 + lane);
            int v3 = __builtin_nontemporal_load(ar + (it + 3) * 64 + lane);
            unsigned long long b0 = __ballot(v0 != 0);
            unsigned long long b1 = __ballot(v1 != 0);
            unsigned long long b2 = __ballot(v2 != 0);
            unsigned long long b3 = __ballot(v3 != 0);
            if (lane == 0) {
                outp[it + 0] = b0;
                outp[it + 1] = b1;
                outp[it + 2] = b2;
                outp[it + 3] = b3;
            }
        }
        return;
    }

    int q = bid - 8192;            // 0..1535
    int mat = q >> 9;              // 0=Q,1=K,2=V
    int rem = q & 511;
    int fb = rem & 7;              // head
    int mb = rem >> 3;             // 0..63
    int la = lane & 15, lk = lane >> 4;

    int m_base = mb * 64 + wave * 16;
    int f_base = fb * 64;

    const ushort* xb = ws + X_OFF;
    const ushort* wb = ws + W_OFF + mat * 262144;

    f32x4 acc[4];
#pragma unroll
    for (int t = 0; t < 4; ++t) acc[t] = (f32x4){0.f, 0.f, 0.f, 0.f};

#pragma unroll 4
    for (int k0 = 0; k0 < 512; k0 += 32) {
        bf16x8 a = *reinterpret_cast<const bf16x8*>(xb + (size_t)(m_base + la) * 512 + k0 + lk * 8);
#pragma unroll
        for (int ft = 0; ft < 4; ++ft) {
            bf16x8 b = *reinterpret_cast<const bf16x8*>(wb + (size_t)(f_base + ft * 16 + la) * 512 + k0 + lk * 8);
            acc[ft] = __builtin_amdgcn_mfma_f32_16x16x32_bf16(a, b, acc[ft], 0, 0, 0);
        }
    }

#pragma unroll
    for (int ft = 0; ft < 4; ++ft) {
#pragma unroll
        for (int r = 0; r < 4; ++r) {
            int n = m_base + lk * 4 + r;
            int d = ft * 16 + la;          // head-local feature
            ushort v = f2bf(acc[ft][r]);
            if (mat < 2) {
                ushort* base = ws + (mat == 0 ? QF_OFF : KF_OFF) + (size_t)fb * 262144;
                int blk = n >> 4, rr = n & 15;
                int half = d >> 5, lkk = (d >> 3) & 3, e = d & 7;
                base[(((size_t)blk * 2 + half) * 64 + lkk * 16 + rr) * 8 + e] = v;
            } else {
                ushort* base = ws + VF_OFF + (size_t)fb * 262144;
                int kb64 = n >> 6, kc = n & 63;
                int hf = kc >> 5, lkv = (kc >> 3) & 3, ev = kc & 7;
                int dt = d >> 4, lav = d & 15;
                base[((((size_t)kb64 * 4 + dt) * 2 + hf) * 64 + lkv * 16 + lav) * 8 + ev] = v;
            }
        }
    }
}

// ---------------- kernel 2: attention — R16 protocol, 32 q-rows/wave, ks=3 -------------
// grid 768 (= 256 CUs x 3, zero tail): h = bid&7, qb = (bid>>3)&31, ks = bid>>8 (0..2).
// 4 waves (256 thr) x 32 q-rows = 128 rows/block; bodies split 22/21/21 over ks.
// Protocol identical to R16 (verified): per body [vmcnt(0) free-drain; barrier] ->
// STAGE(t+1) -> uint2 masks (2 rows/lane) -> swapped QK^T from kbuf (kf shared by
// both q-subtiles) -> fused bit-mask+exp -> b64 P-writes -> PV from vbuf (vb shared).
__global__ __launch_bounds__(256, 3) void attn_kernel(const unsigned int* __restrict__ pk,
                                                      const ushort* __restrict__ ws,
                                                      ushort* __restrict__ pacc,
                                                      float* __restrict__ pden) {
    __shared__ ushort kbuf[2][8][512];    // 16KB
    __shared__ ushort vbuf[2][8][512];    // 16KB
    __shared__ ushort P[4][2][16][72];    // 18KB: [wave][q-subtile][row][k]

    int bid = blockIdx.x;
    int h = bid & 7, qb = (bid >> 3) & 31, ks = bid >> 8;
    int wave = threadIdx.x >> 6, lane = threadIdx.x & 63;
    int la = lane & 15, lk = lane >> 4;
    int q0w = qb * 128 + wave * 32;
    int lk4 = lk * 4;

    const ushort* Qh = ws + QF_OFF + (size_t)h * 262144;
    const ushort* Kh = ws + KF_OFF + (size_t)h * 262144;
    const ushort* Vh = ws + VF_OFF + (size_t)h * 262144;
    const unsigned int* mrow0 = pk + ((size_t)h * 4096 + q0w + la) * 128;
    const unsigned int* mrow1 = mrow0 + 16 * 128;

    // Q fragments for both subtiles (B-operand of swapped QK^T)
    bf16x8 qa[2][2];
#pragma unroll
    for (int qs = 0; qs < 2; ++qs)
#pragma unroll
        for (int hf = 0; hf < 2; ++hf)
            qa[qs][hf] = *reinterpret_cast<const bf16x8*>(
                Qh + ((((size_t)((q0w >> 4) + qs)) * 2 + hf) * 64 + lane) * 8);

    f32x4 acc[2][4];
    float den[2] = {0.f, 0.f};
#pragma unroll
    for (int qs = 0; qs < 2; ++qs)
#pragma unroll
        for (int r = 0; r < 4; ++r) acc[qs][r] = (f32x4){0.f, 0.f, 0.f, 0.f};

    const f32x4 zero = {0.f, 0.f, 0.f, 0.f};
    int kb_begin = ks * 21 + (ks ? 1 : 0);     // {0, 22, 43}
    int kb_count = 22 - (ks ? 1 : 0);          // {22, 21, 21}

#define STAGE(BUF, KB)                                                                     \
    {                                                                                      \
        const ushort* sbase_ = (wave < 2) ? Kh : Vh;                                       \
        ushort(*dbuf_)[512] = (wave < 2) ? kbuf[BUF] : vbuf[BUF];                          \
        int t0_ = (wave & 1) * 4;                                                          \
        _Pragma("unroll")                                                                  \
        for (int t_ = 0; t_ < 4; ++t_) {                                                   \
            int tile_ = t0_ + t_;                                                          \
            const ushort* src_ = sbase_ +                                                  \
                (((size_t)(KB) * 4 + (tile_ >> 1)) * 2 + (tile_ & 1)) * 512 + lane * 8;    \
            __builtin_amdgcn_global_load_lds(                                              \
                (const __attribute__((address_space(1))) unsigned int*)src_,               \
                (__attribute__((address_space(3))) unsigned int*)&dbuf_[tile_][0],         \
                16, 0, 0);                                                                 \
        }                                                                                  \
    }

    STAGE(0, kb_begin)

    for (int it = 0; it < kb_count; ++it) {
        int kb = kb_begin + it;
        int cur = it & 1;

        // only own stage ops (issued one body ago) are outstanding -> free drain
        asm volatile("s_waitcnt vmcnt(0)" ::: "memory");
        __builtin_amdgcn_s_barrier();

        if (it + 1 < kb_count) STAGE(cur ^ 1, kb + 1)

        // masks: one uint2 per lane per subtile (rows q0w+la, q0w+16+la)
        uint2 mk0 = *reinterpret_cast<const uint2*>(mrow0 + kb * 2);
        uint2 mk1 = *reinterpret_cast<const uint2*>(mrow1 + kb * 2);

        // swapped QK^T from LDS: kf shared by both q-subtiles
#pragma unroll
        for (int kt = 0; kt < 4; ++kt) {
            bf16x8 kf0 = *reinterpret_cast<const bf16x8*>(&kbuf[cur][kt * 2 + 0][lane * 8]);
            bf16x8 kf1 = *reinterpret_cast<const bf16x8*>(&kbuf[cur][kt * 2 + 1][lane * 8]);
            int sh = ((kt & 1) << 4) + lk4;
#pragma unroll
            for (int qs = 0; qs < 2; ++qs) {
                f32x4 s = __builtin_amdgcn_mfma_f32_16x16x32_bf16(kf0, qa[qs][0], zero, 0, 0, 0);
                s = __builtin_amdgcn_mfma_f32_16x16x32_bf16(kf1, qa[qs][1], s, 0, 0, 0);
                unsigned int dw = qs ? ((kt < 2) ? mk1.x : mk1.y) : ((kt < 2) ? mk0.x : mk0.y);
                ushort4 pw;
                float e0 = __expf(((dw >> (sh + 0)) & 1u) ? s[0] : -1e30f);
                float e1 = __expf(((dw >> (sh + 1)) & 1u) ? s[1] : -1e30f);
                float e2 = __expf(((dw >> (sh + 2)) & 1u) ? s[2] : -1e30f);
                float e3 = __expf(((dw >> (sh + 3)) & 1u) ? s[3] : -1e30f);
                den[qs] += (e0 + e1) + (e2 + e3);
                pw.x = f2bf(e0); pw.y = f2bf(e1); pw.z = f2bf(e2); pw.w = f2bf(e3);
                *reinterpret_cast<ushort4*>(&P[wave][qs][la][kt * 16 + lk4]) = pw;
            }
        }

        // PV: pa per subtile; vb shared across subtiles
        bf16x8 pa[2][2];
#pragma unroll
        for (int qs = 0; qs < 2; ++qs) {
            pa[qs][0] = *reinterpret_cast<const bf16x8*>(&P[wave][qs][la][lk * 8]);
            pa[qs][1] = *reinterpret_cast<const bf16x8*>(&P[wave][qs][la][32 + lk * 8]);
        }
#pragma unroll
        for (int dt = 0; dt < 4; ++dt) {
            bf16x8 vb0 = *reinterpret_cast<const bf16x8*>(&vbuf[cur][dt * 2 + 0][lane * 8]);
            bf16x8 vb1 = *reinterpret_cast<const bf16x8*>(&vbuf[cur][dt * 2 + 1][lane * 8]);
            acc[0][dt] = __builtin_amdgcn_mfma_f32_16x16x32_bf16(pa[0][0], vb0, acc[0][dt], 0, 0, 0);
            acc[0][dt] = __builtin_amdgcn_mfma_f32_16x16x32_bf16(pa[0][1], vb1, acc[0][dt], 0, 0, 0);
            acc[1][dt] = __builtin_amdgcn_mfma_f32_16x16x32_bf16(pa[1][0], vb0, acc[1][dt], 0, 0, 0);
            acc[1][dt] = __builtin_amdgcn_mfma_f32_16x16x32_bf16(pa[1][1], vb1, acc[1][dt], 0, 0, 0);
        }
    }

    // den: reduce over the 4 lk groups; every lane ends with its row's full sum
#pragma unroll
    for (int qs = 0; qs < 2; ++qs) {
        den[qs] += __shfl_xor(den[qs], 16, 64);
        den[qs] += __shfl_xor(den[qs], 32, 64);
    }

    // store bf16 partial acc (D row q = qs*16 + lk4 + r, col d = dt*16 + la)
    ushort* pa_out = pacc + ((size_t)ks * 8 + h) * 4096 * 64;
#pragma unroll
    for (int qs = 0; qs < 2; ++qs)
#pragma unroll
        for (int dt = 0; dt < 4; ++dt)
#pragma unroll
            for (int r = 0; r < 4; ++r) {
                int qi = q0w + qs * 16 + lk4 + r;
                __builtin_nontemporal_store(f2bf(acc[qs][dt][r]), pa_out + (size_t)qi * 64 + dt * 16 + la);
            }
    if (lane < 16) {
        float* pd = pden + ((size_t)ks * 8 + h) * 4096;
        pd[q0w + lane] = den[0];
        pd[q0w + 16 + lane] = den[1];
    }
#undef STAGE
}

// ---------------- kernel 3: combine bf16 partials + epilogue ----------------
__global__ __launch_bounds__(256) void combine_kernel(const float* __restrict__ x,
                                                      const ushort* __restrict__ pacc,
                                                      const float* __restrict__ pden,
                                                      float* __restrict__ out) {
    int idx = blockIdx.x * 256 + threadIdx.x;   // 524288 total
    int n = idx >> 7, fq = idx & 127;
    int h = fq >> 4;
    int d4 = (fq & 15) * 4;

    float4 o = make_float4(0.f, 0.f, 0.f, 0.f);
    float den = 0.f;
#pragma unroll
    for (int ksp = 0; ksp < 3; ++ksp) {
        const ushort* pa = pacc + (((size_t)ksp * 8 + h) * 4096 + n) * 64 + d4;
        ushort4 p = *reinterpret_cast<const ushort4*>(pa);
        o.x += bf2f(p.x); o.y += bf2f(p.y); o.z += bf2f(p.z); o.w += bf2f(p.w);
        den += pden[((size_t)ksp * 8 + h) * 4096 + n];
    }
    float4 xv = *reinterpret_cast<const float4*>(x + (size_t)n * 512 + fq * 4);
    float inv = 1.f / den;
    float4 r;
    r.x = o.x * inv + xv.x;
    r.y = o.y * inv + xv.y;
    r.z = o.z * inv + xv.z;
    r.w = o.w * inv + xv.w;
    r.x = (r.x > 0.f) ? r.x : (__expf(r.x) - 1.f);
    r.y = (r.y > 0.f) ? r.y : (__expf(r.y) - 1.f);
    r.z = (r.z > 0.f) ? r.z : (__expf(r.z) - 1.f);
    r.w = (r.w > 0.f) ? r.w : (__expf(r.w) - 1.f);
    *reinterpret_cast<float4*>(out + (size_t)n * 512 + fq * 4) = r;
}

extern "C" void kernel_launch(void* const* d_in, const int* in_sizes, int n_in,
                              void* d_out, int out_size, void* d_ws, size_t ws_size,
                              hipStream_t stream) {
    const float* x  = (const float*)d_in[0];
    const float* wq = (const float*)d_in[1];
    const float* wk = (const float*)d_in[2];
    const float* wv = (const float*)d_in[3];
    const int*   adj = (const int*)d_in[4];
    float* out = (float*)d_out;
    ushort* ws = (ushort*)d_ws;
    ushort* pacc = ws + PACC_OFF;
    float* pden = (float*)(ws + PDEN_USHORT_OFF);
    unsigned int* pk = (unsigned int*)(ws + PK_USHORT_OFF);

    cvt_kernel<<<2816, 256, 0, stream>>>(x, wq, wk, wv, ws);
    packqkv_kernel<<<9728, 256, 0, stream>>>(adj, pk, ws);
    attn_kernel<<<768, 256, 0, stream>>>(pk, ws, pacc, pden);
    combine_kernel<<<2048, 256, 0, stream>>>(x, pacc, pden, out);
}